// Round 11
// baseline (801.040 us; speedup 1.0000x reference)
//
#include <hip/hip_runtime.h>

// RGCN 3-layer forward, MI355X — fully fused aggregate+transform v6.
// Identity: sum_e x[src_e] @ W_r == (sum_e x[src_e]) @ W_r.
// Round-10 lesson: decoupled agg/gemm is bound by the Y round-trip (~400MB/layer
// HBM+L3) and Y streaming evicts x from L3. v6 fuses per 64-row tile: per rel,
// waves aggregate 16 rows each (static 2-edge register prefetch = r10's proven
// ILP pattern) into a swizzled LDS Y-tile, then col-split MFMA (B-reuse 4x,
// r8's proven pattern) accumulates into persistent registers; loads for rel r+1
// issue alongside MFMA(r). Root transform from an X-tile staged once via
// global_load_lds. Y never touches global memory.
// Sort v5 (coarse bins + in-LDS fine sort) unchanged.

#define DEVI __device__ __forceinline__

typedef __attribute__((ext_vector_type(8))) short bf16x8;
typedef __attribute__((ext_vector_type(4))) float f32x4;

DEVI unsigned short f2b(float f) {
  unsigned int u = __builtin_bit_cast(unsigned int, f);
  unsigned int r = (u + 0x7FFFu + ((u >> 16) & 1u)) >> 16;
  return (unsigned short)r;
}
DEVI float b2f(unsigned short h) {
  unsigned int u = ((unsigned int)h) << 16;
  return __builtin_bit_cast(float, u);
}
DEVI float lo16f(unsigned v) { return __builtin_bit_cast(float, v << 16); }
DEVI float hi16f(unsigned v) { return __builtin_bit_cast(float, v & 0xFFFF0000u); }
DEVI int imin(int a, int b) { return a < b ? a : b; }

// ---------------- sort v5: coarse bins = rel*NG + (tile>>7) ----------------

__global__ void k_zero2(int* __restrict__ cnt, int n) {
  int stride = gridDim.x * blockDim.x;
  for (int i = blockIdx.x * blockDim.x + threadIdx.x; i < n; i += stride) cnt[i] = 0;
}

__global__ void k_chist(const int* __restrict__ et, const int* __restrict__ edst,
                        int* __restrict__ gh, int NG, int E) {
  __shared__ int h[128];
  if (threadIdx.x < 128) h[threadIdx.x] = 0;
  __syncthreads();
  int stride = gridDim.x * blockDim.x;
  for (int i = blockIdx.x * blockDim.x + threadIdx.x; i < E; i += stride)
    atomicAdd(&h[(et[i] & 7) * NG + (edst[i] >> 13)], 1);
  __syncthreads();
  if (threadIdx.x < 128) atomicAdd(&gh[threadIdx.x], h[threadIdx.x]);
}

__global__ void k_cscan(const int* __restrict__ gh, int* __restrict__ gcursor,
                        int* __restrict__ cbase, int NBC, int E) {
  if (threadIdx.x == 0) {
    int a = 0;
    for (int b = 0; b < NBC; ++b) { cbase[b] = a; gcursor[b] = a; a += gh[b]; }
    cbase[NBC] = E;
  }
}

__launch_bounds__(256)
__global__ void k_cfill(const int* __restrict__ et, const int* __restrict__ esrc,
                        const int* __restrict__ edst, int* __restrict__ gcursor,
                        int* __restrict__ stage, int NG, int E) {
  __shared__ int h[128], base[128], lc[128];
  int nb = gridDim.x;
  int slice = (E + nb - 1) / nb;
  int lo = blockIdx.x * slice;
  int hi = lo + slice < E ? lo + slice : E;
  int t = threadIdx.x;
  if (t < 128) { h[t] = 0; lc[t] = 0; }
  __syncthreads();
  for (int i = lo + t; i < hi; i += 256)
    atomicAdd(&h[(et[i] & 7) * NG + (edst[i] >> 13)], 1);
  __syncthreads();
  if (t < 128 && h[t] > 0) base[t] = atomicAdd(&gcursor[t], h[t]);
  __syncthreads();
  for (int i = lo + t; i < hi; i += 256) {
    int d = edst[i];
    int tile = d >> 6;
    int bin = (et[i] & 7) * NG + (tile >> 7);
    int p = base[bin] + atomicAdd(&lc[bin], 1);
    stage[p] = ((tile & 127) << 23) | ((d & 63) << 17) | esrc[i];
  }
}

__launch_bounds__(1024)
__global__ void k_fine(const int* __restrict__ cbase, const int* __restrict__ stage,
                       int* __restrict__ srcl, int* __restrict__ lo9,
                       int* __restrict__ len9, int NG, int NTr) {
  __shared__ int h[8192];
  __shared__ int tsum[1024];
  __shared__ int wsum[16];
  int b = blockIdx.x;
  int rel = b / NG, tg = b - rel * NG;
  int lo = cbase[b], hi = cbase[b + 1];
  int t = threadIdx.x;
  for (int k = t; k < 8192; k += 1024) h[k] = 0;
  __syncthreads();
  for (int i = lo + t; i < hi; i += 1024)
    atomicAdd(&h[(stage[i] >> 17) & 0x1FFF], 1);
  __syncthreads();
  int dbase = tg * 8192;
  size_t relbase = (size_t)rel * NTr;
  for (int k = t; k < 8192; k += 1024) {
    int d = dbase + k;
    if (d < NTr) len9[relbase + d] = h[k];
  }
  int loc[8];
  int s = 0;
  int kb = t * 8;
#pragma unroll
  for (int j = 0; j < 8; ++j) { loc[j] = s; s += h[kb + j]; }
  tsum[t] = s;
  __syncthreads();
  int lane = t & 63, w = t >> 6;
  int v = tsum[t];
#pragma unroll
  for (int o = 1; o < 64; o <<= 1) {
    int u = __shfl_up(v, o);
    if (lane >= o) v += u;
  }
  if (lane == 63) wsum[w] = v;
  __syncthreads();
  if (t == 0) {
    int a = 0;
#pragma unroll
    for (int j = 0; j < 16; ++j) { int tmp = wsum[j]; wsum[j] = a; a += tmp; }
  }
  __syncthreads();
  int texcl = v - s + wsum[w];
#pragma unroll
  for (int j = 0; j < 8; ++j) h[kb + j] = texcl + loc[j];
  __syncthreads();
  for (int k = t; k < 8192; k += 1024) {
    int d = dbase + k;
    if (d < NTr) lo9[relbase + d] = lo + h[k];
  }
  __syncthreads();
  for (int i = lo + t; i < hi; i += 1024) {
    int pk = stage[i];
    int key = (pk >> 17) & 0x1FFF;
    int p = atomicAdd(&h[key], 1);
    srcl[lo + p] = pk & 0x1FFFF;
  }
}

// ---------------- weight prep: fp32 [9][128][DOUT] -> bf16 [9][DOUT][128] ----------------

__global__ void wprep_kernel(const float* __restrict__ Wrel, const float* __restrict__ Wroot,
                             unsigned short* __restrict__ wt, int DOUT) {
  int total = 9 * 128 * DOUT;
  int stride = gridDim.x * blockDim.x;
  for (int i = blockIdx.x * blockDim.x + threadIdx.x; i < total; i += stride) {
    int k = i & 127;
    int oo = i >> 7;
    int o = oo % DOUT;
    int rr = oo / DOUT;
    float v = (rr < 8) ? Wrel[((size_t)rr * 128 + k) * DOUT + o]
                       : Wroot[(size_t)k * DOUT + o];
    wt[i] = f2b(v);
  }
}

// ---------------- fused layer v6 ----------------
// block = 64 dst rows, 4 waves. Per rel: waves aggregate 16 rows each into a
// swizzled LDS Y-tile (2-edge register prefetch per row), then col-split MFMA.

template <int DOUT, bool LSM>
__launch_bounds__(256)
__global__ void fused_layer(const unsigned short* __restrict__ xb,  // [NTr][128] bf16
                            const unsigned short* __restrict__ wt,  // [9][DOUT][128] bf16
                            const int* __restrict__ lo9,            // [8*NTr] rel-major
                            const int* __restrict__ len9,
                            const int* __restrict__ srcl,
                            const float* __restrict__ bias,
                            unsigned short* __restrict__ out_b,
                            float* __restrict__ out_f,
                            int N, int NTr, int E) {
  __shared__ unsigned short XY[2 * 64 * 128];   // [0..8191]=X tile, [8192..]=Y tile
  __shared__ int ll0[512], ll1[512];
  unsigned short* Xl = XY;
  unsigned short* Yl = XY + 8192;
  constexpr int NF = (DOUT == 128) ? 2 : 1;
  int tid = threadIdx.x, wid = tid >> 6, lane = tid & 63;
  int colb = lane & 15, kgrp = lane >> 4;
  int colw = wid * 16 * NF;
  int tilebase = blockIdx.x * 64;
  const unsigned* x32 = (const unsigned*)xb;

  // ---- stage X tile (swizzled via pre-swizzled global source) ----
  {
    const unsigned short* sa = xb + (size_t)tilebase * 128;
#pragma unroll
    for (int q = 0; q < 4; ++q) {
      int c = q * 256 + tid;
      int row = c >> 4, kcl = c & 15;
      int kcg = kcl ^ (row & 7);
      const unsigned short* gp = sa + (size_t)row * 128 + kcg * 8;
      unsigned short* lp = &Xl[(q * 256 + (tid & ~63)) * 8];
      __builtin_amdgcn_global_load_lds(
          (__attribute__((address_space(1))) void*)gp,
          (__attribute__((address_space(3))) void*)lp, 16, 0, 0);
    }
  }
  // ---- preload segment table (64 rows x 8 rels) ----
#pragma unroll
  for (int q = 0; q < 2; ++q) {
    int idx = q * 256 + tid;
    int r = idx >> 6, c = idx & 63;
    size_t g = (size_t)r * NTr + tilebase + c;
    ll0[idx] = lo9[g];
    ll1[idx] = len9[g];
  }

  f32x4 acc[4][NF];
#pragma unroll
  for (int rb = 0; rb < 4; ++rb)
#pragma unroll
    for (int nf = 0; nf < NF; ++nf) {
      f32x4 z = {0.f, 0.f, 0.f, 0.f};
      acc[rb][nf] = z;
    }

  // prefetched aggregation state: 16 rows/wave, first 2 edges each
  int s_lo[16], s_ln[16];
  unsigned s_v0[16], s_v1[16];

  auto aggLoad = [&](int r) {
#pragma unroll
    for (int j = 0; j < 16; ++j) {
      int row = wid * 16 + j;
      int lo = ll0[r * 64 + row];
      int ln = ll1[r * 64 + row];
      s_lo[j] = lo;
      s_ln[j] = ln;
      int a = srcl[imin(lo, E - 1)];
      int b = srcl[imin(lo + 1, E - 1)];
      s_v0[j] = x32[(size_t)a * 64 + lane];
      s_v1[j] = x32[(size_t)b * 64 + lane];
    }
  };

  auto aggFinish = [&]() {
    unsigned* Yd = (unsigned*)Yl;
#pragma unroll
    for (int j = 0; j < 16; ++j) {
      int row = wid * 16 + j;
      float a0 = 0.f, a1 = 0.f;
      int lo = s_lo[j], ln = s_ln[j];
      if (ln > 0) { a0 += lo16f(s_v0[j]); a1 += hi16f(s_v0[j]); }
      if (ln > 1) { a0 += lo16f(s_v1[j]); a1 += hi16f(s_v1[j]); }
      for (int i = lo + 2; i < lo + ln; ++i) {
        unsigned v = x32[(size_t)srcl[i] * 64 + lane];
        a0 += lo16f(v);
        a1 += hi16f(v);
      }
      int c = lane >> 2;
      int pos = row * 64 + ((c ^ (row & 7)) << 2) + (lane & 3);
      Yd[pos] = (unsigned)f2b(a0) | ((unsigned)f2b(a1) << 16);
    }
  };

  auto mfmaStep = [&](const unsigned short* Ab, const unsigned short* W) {
#pragma unroll
    for (int kk = 0; kk < 4; ++kk) {
      int kc = kk * 4 + kgrp;
      bf16x8 a[4];
#pragma unroll
      for (int rb = 0; rb < 4; ++rb) {
        int arow = rb * 16 + colb;
        a[rb] = *(const bf16x8*)(Ab + (size_t)(arow * 16 + (kc ^ (arow & 7))) * 8);
      }
#pragma unroll
      for (int nf = 0; nf < NF; ++nf) {
        bf16x8 b = *(const bf16x8*)(W + (size_t)(colw + nf * 16 + colb) * 128 + kc * 8);
#pragma unroll
        for (int rb = 0; rb < 4; ++rb)
          acc[rb][nf] = __builtin_amdgcn_mfma_f32_16x16x32_bf16(a[rb], b, acc[rb][nf], 0, 0, 0);
      }
    }
  };

  __syncthreads();                 // X tile + ll ready
  aggLoad(0);                      // rel-0 loads fly under root MFMA
  mfmaStep(Xl, wt + (size_t)8 * DOUT * 128);   // root transform

  for (int r = 0; r < 8; ++r) {
    __syncthreads();               // Y tile free (prev MFMA done); drains loads
    aggFinish();                   // accumulate + swizzled ds_write
    __syncthreads();               // Y tile ready
    mfmaStep(Yl, wt + (size_t)r * DOUT * 128);
    if (r < 7) aggLoad(r + 1);     // issue next-rel loads (scheduler interleaves)
  }

  // ---- epilogue ----
  if (LSM) {
    // DOUT==64 log-softmax: stage fp32 rows into LDS, reduce per row
    float* Lf = (float*)XY;        // 64 x 68 padded (17.4 KB of 32 KB)
    float bv = bias[colw + colb];
    __syncthreads();               // all MFMA ds_reads of XY done
#pragma unroll
    for (int rb = 0; rb < 4; ++rb)
#pragma unroll
      for (int i = 0; i < 4; ++i) {
        int row = rb * 16 + kgrp * 4 + i;
        Lf[row * 68 + colw + colb] = acc[rb][0][i] + bv;
      }
    __syncthreads();
#pragma unroll
    for (int it = 0; it < 4; ++it) {
      int row = wid * 16 + it * 4 + kgrp;
      float v[4];
#pragma unroll
      for (int j = 0; j < 4; ++j) v[j] = Lf[row * 68 + colb + j * 16];
      float m = fmaxf(fmaxf(v[0], v[1]), fmaxf(v[2], v[3]));
#pragma unroll
      for (int s = 1; s < 16; s <<= 1) m = fmaxf(m, __shfl_xor(m, s));
      float sum = 0.f;
#pragma unroll
      for (int j = 0; j < 4; ++j) sum += __expf(v[j] - m);
#pragma unroll
      for (int s = 1; s < 16; s <<= 1) sum += __shfl_xor(sum, s);
      float lse = m + __logf(sum);
      int grow = tilebase + row;
      if (grow < N) {
#pragma unroll
        for (int j = 0; j < 4; ++j)
          out_f[(size_t)grow * 64 + colb + j * 16] = v[j] - lse;
      }
    }
  } else {
    float bv[NF];
#pragma unroll
    for (int nf = 0; nf < NF; ++nf) bv[nf] = bias[colw + nf * 16 + colb];
#pragma unroll
    for (int rb = 0; rb < 4; ++rb)
#pragma unroll
      for (int i = 0; i < 4; ++i) {
        int row = tilebase + rb * 16 + kgrp * 4 + i;
        if (row >= N) continue;
#pragma unroll
        for (int nf = 0; nf < NF; ++nf) {
          int col = colw + nf * 16 + colb;
          float v = acc[rb][nf][i] + bv[nf];
          out_b[(size_t)row * DOUT + col] = f2b(fmaxf(v, 0.f));
        }
      }
  }
}

// ---------------- input cast ----------------

__global__ void cast_kernel(const float* __restrict__ in, unsigned short* __restrict__ out,
                            int n4) {
  int stride = gridDim.x * blockDim.x;
  for (int i = blockIdx.x * blockDim.x + threadIdx.x; i < n4; i += stride) {
    float4 v = ((const float4*)in)[i];
    ushort4 o;
    o.x = f2b(v.x); o.y = f2b(v.y); o.z = f2b(v.z); o.w = f2b(v.w);
    ((ushort4*)out)[i] = o;
  }
}

// ---------------- launch ----------------

extern "C" void kernel_launch(void* const* d_in, const int* in_sizes, int n_in,
                              void* d_out, int out_size, void* d_ws, size_t ws_size,
                              hipStream_t stream) {
  const float* x = (const float*)d_in[0];
  const int* eidx = (const int*)d_in[1];
  const int* et = (const int*)d_in[2];
  const float* Wrel1 = (const float*)d_in[3];
  const float* Wroot1 = (const float*)d_in[4];
  const float* b1 = (const float*)d_in[5];
  const float* Wrel2 = (const float*)d_in[6];
  const float* Wroot2 = (const float*)d_in[7];
  const float* b2 = (const float*)d_in[8];
  const float* Wrel3 = (const float*)d_in[9];
  const float* Wroot3 = (const float*)d_in[10];
  const float* b3 = (const float*)d_in[11];

  const int N = in_sizes[0] / 128;    // 100000
  const int E = in_sizes[2];          // 1600000
  const int NT = (N + 63) / 64;       // 1563
  const int NTr = NT * 64;            // 100032
  const int NG = (NT + 127) / 128;    // 13
  const int NBC = 8 * NG;             // 104
  const int* esrc = eidx;
  const int* edst = eidx + E;

  const size_t XB = (size_t)NTr * 128 * 2;   // 25.6 MB

  char* p = (char*)d_ws;
  auto carve = [&](size_t bytes) {
    void* q = (void*)p;
    p += (bytes + 255) & ~(size_t)255;
    return q;
  };
  unsigned short* bufX0 = (unsigned short*)carve(XB);
  unsigned short* bufX1 = (unsigned short*)carve(XB);
  unsigned short* wt1 = (unsigned short*)carve((size_t)9 * 128 * 128 * 2);
  unsigned short* wt2 = (unsigned short*)carve((size_t)9 * 128 * 128 * 2);
  unsigned short* wt3 = (unsigned short*)carve((size_t)9 * 64 * 128 * 2);
  int* stage = (int*)carve((size_t)E * 4);
  int* srcl = (int*)carve((size_t)E * 4);
  int* lo9 = (int*)carve((size_t)8 * NTr * 4);
  int* len9 = (int*)carve((size_t)8 * NTr * 4);
  int* gh = (int*)carve(512);
  int* gcursor = (int*)carve(512);
  int* cbase = (int*)carve(512);

  // ---- sort v5 (once; reused by all 3 layers) ----
  k_zero2<<<1, 128, 0, stream>>>(gh, 128);
  k_chist<<<512, 256, 0, stream>>>(et, edst, gh, NG, E);
  k_cscan<<<1, 64, 0, stream>>>(gh, gcursor, cbase, NBC, E);
  k_cfill<<<512, 256, 0, stream>>>(et, esrc, edst, gcursor, stage, NG, E);
  k_fine<<<NBC, 1024, 0, stream>>>(cbase, stage, srcl, lo9, len9, NG, NTr);

  // ---- weight prep + input cast ----
  wprep_kernel<<<576, 256, 0, stream>>>(Wrel1, Wroot1, wt1, 128);
  wprep_kernel<<<576, 256, 0, stream>>>(Wrel2, Wroot2, wt2, 128);
  wprep_kernel<<<288, 256, 0, stream>>>(Wrel3, Wroot3, wt3, 64);
  cast_kernel<<<2048, 256, 0, stream>>>(x, bufX0, N * 128 / 4);

  // ---- 3 fused layers ----
  fused_layer<128, false><<<NT, 256, 0, stream>>>(bufX0, wt1, lo9, len9, srcl, b1,
                                                  bufX1, (float*)nullptr, N, NTr, E);
  fused_layer<128, false><<<NT, 256, 0, stream>>>(bufX1, wt2, lo9, len9, srcl, b2,
                                                  bufX0, (float*)nullptr, N, NTr, E);
  fused_layer<64, true><<<NT, 256, 0, stream>>>(bufX0, wt3, lo9, len9, srcl, b3,
                                                (unsigned short*)nullptr, (float*)d_out,
                                                N, NTr, E);
}